// Round 1
// baseline (854.054 us; speedup 1.0000x reference)
//
#include <hip/hip_runtime.h>
#include <cstdio>

// Qwen2 MoE sparse block, MI355X gfx950.
// Round 1: bf16-MFMA pipeline. Weights converted+transposed fp32->bf16 once per
// call into d_ws; all GEMMs use the m97-style 128x128 tile, BK=32,
// global_load_lds(16B) staging, mfma_f32_16x16x32_bf16.

#define H_DIM 2048
#define IMOE  1408
#define ISH   5632
#define NEXP  8
#define T_TOK 2048
#define TK_TOT (T_TOK * 2)   // total routed slots (top-2, always 4096)

typedef __attribute__((ext_vector_type(8))) short short8;
typedef __attribute__((ext_vector_type(8))) __bf16 bf16x8;
typedef __attribute__((ext_vector_type(4))) float f32x4;

__device__ __forceinline__ float bf2f(unsigned short u) {
  union { unsigned int i; float f; } v; v.i = ((unsigned int)u) << 16; return v.f;
}
__device__ __forceinline__ unsigned short f2bf(float f) {
  union { float f; unsigned int i; } v; v.f = f;
  unsigned int x = v.i;
  return (unsigned short)((x + 0x7fffu + ((x >> 16) & 1u)) >> 16);
}

__device__ __forceinline__ f32x4 MFMA16(short8 a, short8 b, f32x4 c) {
  return __builtin_amdgcn_mfma_f32_16x16x32_bf16(
      __builtin_bit_cast(bf16x8, a), __builtin_bit_cast(bf16x8, b), c, 0, 0, 0);
}

__device__ __forceinline__ void gload_lds16(const unsigned short* g, unsigned short* l) {
  __builtin_amdgcn_global_load_lds(
      (const __attribute__((address_space(1))) unsigned int*)g,
      (__attribute__((address_space(3))) unsigned int*)l, 16, 0, 0);
}

__device__ __forceinline__ float silu_f(float x) { return x / (1.0f + __expf(-x)); }

// ---------------- conversion kernels ----------------

// fp32 [R][C] row-major  ->  bf16 [C][R] row-major (i.e. transposed), batched over z
__global__ __launch_bounds__(256)
void transpose_cvt_kernel(const float* __restrict__ src, unsigned short* __restrict__ dst,
                          int R, int C, long sStride, long dStride) {
  src += (long)blockIdx.z * sStride;
  dst += (long)blockIdx.z * dStride;
  __shared__ float tile[32][33];
  int tx = threadIdx.x, ty = threadIdx.y;           // 32 x 8
  int x = blockIdx.x * 32 + tx;                     // column in src
  int yb = blockIdx.y * 32;
#pragma unroll
  for (int j = 0; j < 4; j++) {
    int y = yb + ty + j * 8;
    tile[ty + j * 8][tx] = src[(long)y * C + x];
  }
  __syncthreads();
  int c = blockIdx.x * 32 + ty;                     // dst row (= src column)
  int r = yb + tx;                                  // dst col (= src row)
#pragma unroll
  for (int j = 0; j < 4; j++) {
    dst[(long)(c + j * 8) * R + r] = f2bf(tile[tx][ty + j * 8]);
  }
}

__global__ __launch_bounds__(256)
void cvt_x_kernel(const float* __restrict__ x, unsigned short* __restrict__ xb, int total4) {
  int i = blockIdx.x * 256 + threadIdx.x;
  if (i >= total4) return;
  float4 v = ((const float4*)x)[i];
  ushort4 o;
  o.x = f2bf(v.x); o.y = f2bf(v.y); o.z = f2bf(v.z); o.w = f2bf(v.w);
  ((ushort4*)xb)[i] = o;
}

// ---------------- routing ----------------

__global__ __launch_bounds__(256)
void router_kernel(const float* __restrict__ x, const float* __restrict__ Wr,
                   const float* __restrict__ Wsg, float* __restrict__ rw,
                   int* __restrict__ sel, float* __restrict__ sgate_sig,
                   int* __restrict__ counts) {
  int t = blockIdx.x;
  const float* xr = x + (long)t * H_DIM;
  float p[9];
#pragma unroll
  for (int e = 0; e < 9; e++) p[e] = 0.0f;
  for (int h = threadIdx.x; h < H_DIM; h += 256) {
    float xv = xr[h];
#pragma unroll
    for (int e = 0; e < 8; e++) p[e] += xv * Wr[e * H_DIM + h];
    p[8] += xv * Wsg[h];
  }
#pragma unroll
  for (int e = 0; e < 9; e++)
    for (int off = 32; off > 0; off >>= 1)
      p[e] += __shfl_down(p[e], off, 64);
  __shared__ float red[4][9];
  int wave = threadIdx.x >> 6, lane = threadIdx.x & 63;
  if (lane == 0) {
#pragma unroll
    for (int e = 0; e < 9; e++) red[wave][e] = p[e];
  }
  __syncthreads();
  if (threadIdx.x == 0) {
    float lg[9];
#pragma unroll
    for (int e = 0; e < 9; e++) lg[e] = red[0][e] + red[1][e] + red[2][e] + red[3][e];
    float m = lg[0];
#pragma unroll
    for (int e = 1; e < 8; e++) m = fmaxf(m, lg[e]);
    float pr[8], s = 0.0f;
#pragma unroll
    for (int e = 0; e < 8; e++) { pr[e] = expf(lg[e] - m); s += pr[e]; }
    float inv = 1.0f / s;
#pragma unroll
    for (int e = 0; e < 8; e++) pr[e] *= inv;
    int i0 = 0;
#pragma unroll
    for (int e = 1; e < 8; e++) if (pr[e] > pr[i0]) i0 = e;
    int i1 = (i0 == 0) ? 1 : 0;
#pragma unroll
    for (int e = 0; e < 8; e++) if (e != i0 && pr[e] > pr[i1]) i1 = e;
    rw[t * 2] = pr[i0]; rw[t * 2 + 1] = pr[i1];
    sel[t * 2] = i0;    sel[t * 2 + 1] = i1;
    sgate_sig[t] = 1.0f / (1.0f + expf(-lg[8]));
    atomicAdd(&counts[i0], 1);
    atomicAdd(&counts[i1], 1);
  }
}

__global__ void scan_kernel(const int* __restrict__ counts, int* __restrict__ offsets) {
  if (threadIdx.x == 0 && blockIdx.x == 0) {
    int s = 0;
    for (int e = 0; e < NEXP; e++) { offsets[e] = s; s += counts[e]; }
    offsets[NEXP] = s;
  }
}

__global__ __launch_bounds__(256)
void scatter_kernel(const int* __restrict__ sel, const int* __restrict__ offsets,
                    int* __restrict__ cursor, int* __restrict__ tok_of_slot,
                    int* __restrict__ slot_of_tok) {
  int t = blockIdx.x * 256 + threadIdx.x;
  if (t >= T_TOK) return;
#pragma unroll
  for (int k = 0; k < 2; k++) {
    int e = sel[t * 2 + k];
    int pos = atomicAdd(&cursor[e], 1);
    int slot = offsets[e] + pos;
    tok_of_slot[slot] = t;
    slot_of_tok[t * 2 + k] = slot;
  }
}

// ---------------- GEMM: C[M,N] = A[M,K](bf16) * BT[N,K]^T(bf16) ----------------
// EPI: 0 = store bf16, 1 = store fp32 * rowscale[row], 2 = store fp32
template <int EPI, bool EXPERT, bool GATHER>
__global__ __launch_bounds__(256, 2)
void gemm_bt_kernel(const unsigned short* __restrict__ A,
                    const unsigned short* __restrict__ BT,
                    void* __restrict__ Cv, int M, int N, int K,
                    const int* __restrict__ counts, const int* __restrict__ offsets,
                    const int* __restrict__ tok_of_slot,
                    const float* __restrict__ rowscale, long bt_estride) {
  int cnt = M, rowbase = 0;
  if constexpr (EXPERT) {
    int e = blockIdx.z;
    cnt = counts[e];
    rowbase = offsets[e];
    BT += (long)e * bt_estride;
  }
  int row0 = blockIdx.x * 128;
  if (row0 >= cnt) return;
  int col0 = blockIdx.y * 128;

  __shared__ unsigned short As[128 * 32];
  __shared__ unsigned short Bs[128 * 32];

  int tid = threadIdx.x;
  int wave = tid >> 6, lane = tid & 63;

  // staging: LDS is row-major [128][32]; 16B chunk c -> row c>>2, k (c&3)*8
  int c0 = wave * 64 + lane;
  int c1 = c0 + 256;
  int ar0 = c0 >> 2, ak0 = (c0 & 3) * 8;
  int ar1 = c1 >> 2, ak1 = (c1 & 3) * 8;

  long ga0, ga1;
  {
    int r0 = row0 + ar0, r1 = row0 + ar1;
    if constexpr (EXPERT) {
      int s0 = rowbase + min(r0, cnt - 1);
      int s1 = rowbase + min(r1, cnt - 1);
      if constexpr (GATHER) { ga0 = tok_of_slot[s0]; ga1 = tok_of_slot[s1]; }
      else { ga0 = s0; ga1 = s1; }
    } else { ga0 = r0; ga1 = r1; }
  }
  const unsigned short* aS0 = A + ga0 * (long)K + ak0;
  const unsigned short* aS1 = A + ga1 * (long)K + ak1;
  const unsigned short* bS0 = BT + (long)(col0 + ar0) * K + ak0;
  const unsigned short* bS1 = BT + (long)(col0 + ar1) * K + ak1;

  unsigned short* lA0 = &As[wave * 512];
  unsigned short* lA1 = &As[(4 + wave) * 512];
  unsigned short* lB0 = &Bs[wave * 512];
  unsigned short* lB1 = &Bs[(4 + wave) * 512];

  int wr = (wave >> 1) * 64, wc = (wave & 1) * 64;
  int fr = lane & 15, fg = lane >> 4;

  f32x4 acc[4][4] = {};

  for (int k = 0; k < K; k += 32) {
    gload_lds16(aS0 + k, lA0);
    gload_lds16(aS1 + k, lA1);
    gload_lds16(bS0 + k, lB0);
    gload_lds16(bS1 + k, lB1);
    __syncthreads();
    short8 aF[4], bF[4];
#pragma unroll
    for (int m = 0; m < 4; m++)
      aF[m] = *(const short8*)&As[(wr + m * 16 + fr) * 32 + fg * 8];
#pragma unroll
    for (int n = 0; n < 4; n++)
      bF[n] = *(const short8*)&Bs[(wc + n * 16 + fr) * 32 + fg * 8];
#pragma unroll
    for (int m = 0; m < 4; m++)
#pragma unroll
      for (int n = 0; n < 4; n++)
        acc[m][n] = MFMA16(aF[m], bF[n], acc[m][n]);
    __syncthreads();
  }

#pragma unroll
  for (int m = 0; m < 4; m++) {
    int rbase = wr + m * 16 + fg * 4;
#pragma unroll
    for (int n = 0; n < 4; n++) {
      int cg = col0 + wc + n * 16 + fr;
      f32x4 v = acc[m][n];
#pragma unroll
      for (int r = 0; r < 4; r++) {
        int rl = rbase + r;
        if (row0 + rl < cnt) {
          long orow = (long)(EXPERT ? rowbase : 0) + row0 + rl;
          long ci = orow * (long)N + cg;
          if constexpr (EPI == 0)      ((unsigned short*)Cv)[ci] = f2bf(v[r]);
          else if constexpr (EPI == 1) ((float*)Cv)[ci] = v[r] * rowscale[orow];
          else                         ((float*)Cv)[ci] = v[r];
        }
      }
    }
  }
}

// ---------------- elementwise ----------------

// gu [rows][2*I] bf16 -> h [rows][I] bf16 = silu(gate) * up
__global__ __launch_bounds__(256)
void silu_mul_kernel(const unsigned short* __restrict__ gu, unsigned short* __restrict__ h,
                     int rows, int I) {
  int i = blockIdx.x * 256 + threadIdx.x;
  int i4 = I >> 2;
  if (i >= rows * i4) return;
  int row = i / i4;
  int ci = (i - row * i4) * 4;
  const unsigned short* g = gu + (long)row * 2 * I + ci;
  ushort4 gv = *(const ushort4*)g;
  ushort4 uv = *(const ushort4*)(g + I);
  ushort4 o;
  o.x = f2bf(silu_f(bf2f(gv.x)) * bf2f(uv.x));
  o.y = f2bf(silu_f(bf2f(gv.y)) * bf2f(uv.y));
  o.z = f2bf(silu_f(bf2f(gv.z)) * bf2f(uv.z));
  o.w = f2bf(silu_f(bf2f(gv.w)) * bf2f(uv.w));
  *(ushort4*)(h + (long)row * I + ci) = o;
}

__global__ __launch_bounds__(256)
void combine_kernel(float* __restrict__ out, const float* __restrict__ eo,
                    const int* __restrict__ slot_of_tok, const float* __restrict__ rw) {
  int i = blockIdx.x * 256 + threadIdx.x;   // over T*H/4
  const int h4n = H_DIM / 4;
  if (i >= T_TOK * h4n) return;
  int t = i / h4n;
  int h4 = i - t * h4n;
  int s0 = slot_of_tok[t * 2], s1 = slot_of_tok[t * 2 + 1];
  float w0 = rw[t * 2], w1 = rw[t * 2 + 1];
  float4 o = ((float4*)out)[i];
  float4 a = ((const float4*)eo)[(long)s0 * h4n + h4];
  float4 b = ((const float4*)eo)[(long)s1 * h4n + h4];
  o.x += w0 * a.x + w1 * b.x;
  o.y += w0 * a.y + w1 * b.y;
  o.z += w0 * a.z + w1 * b.z;
  o.w += w0 * a.w + w1 * b.w;
  ((float4*)out)[i] = o;
}

// ---------------- host ----------------

extern "C" void kernel_launch(void* const* d_in, const int* in_sizes, int n_in,
                              void* d_out, int out_size, void* d_ws, size_t ws_size,
                              hipStream_t stream) {
  (void)in_sizes; (void)n_in; (void)out_size;
  const float* x    = (const float*)d_in[0];
  const float* Wr   = (const float*)d_in[1];
  const float* Wsg  = (const float*)d_in[2];
  const float* Wsgu = (const float*)d_in[3];
  const float* Wsd  = (const float*)d_in[4];
  const float* Wegu = (const float*)d_in[5];
  const float* Wed  = (const float*)d_in[6];
  float* out = (float*)d_out;

  char* ws = (char*)d_ws;
  size_t off = 0;
  auto alloc = [&](size_t b) { size_t o = off; off += (b + 255) & ~(size_t)255; return o; };

  size_t o_xbf   = alloc((size_t)T_TOK * H_DIM * 2);
  size_t o_WsguT = alloc((size_t)2 * ISH * H_DIM * 2);       // also aliased as eo later
  size_t o_WsdT  = alloc((size_t)H_DIM * ISH * 2);
  size_t o_WeguT = alloc((size_t)NEXP * 2 * IMOE * H_DIM * 2);
  size_t o_WedT  = alloc((size_t)NEXP * H_DIM * IMOE * 2);
  size_t o_gush  = alloc((size_t)T_TOK * 2 * ISH * 2);       // also aliased as gu_e + h_e later
  size_t o_hsh   = alloc((size_t)T_TOK * ISH * 2);
  size_t o_ints  = alloc(256);                               // counts[8] cursor[8] offsets[9]
  size_t o_rw    = alloc((size_t)TK_TOT * 4);
  size_t o_sel   = alloc((size_t)TK_TOT * 4);
  size_t o_sg    = alloc((size_t)T_TOK * 4);
  size_t o_tok   = alloc((size_t)TK_TOT * 4);
  size_t o_s2t   = alloc((size_t)TK_TOT * 4);

  if (off > ws_size) {
    fprintf(stderr, "[moe kernel] workspace too small: need %zu have %zu\n", off, ws_size);
    return;
  }

  unsigned short* xbf   = (unsigned short*)(ws + o_xbf);
  unsigned short* WsguT = (unsigned short*)(ws + o_WsguT);
  unsigned short* WsdT  = (unsigned short*)(ws + o_WsdT);
  unsigned short* WeguT = (unsigned short*)(ws + o_WeguT);
  unsigned short* WedT  = (unsigned short*)(ws + o_WedT);
  unsigned short* gu_sh = (unsigned short*)(ws + o_gush);
  unsigned short* h_sh  = (unsigned short*)(ws + o_hsh);
  // aliases (lifetimes disjoint): gu_sh region reused for expert gu/h; WsguT region for eo
  unsigned short* gu_e = (unsigned short*)(ws + o_gush);
  unsigned short* h_e  = (unsigned short*)(ws + o_gush + (size_t)TK_TOT * 2 * IMOE * 2);
  float* eo = (float*)(ws + o_WsguT);

  int* counts  = (int*)(ws + o_ints);
  int* cursor  = counts + 8;
  int* offsets = counts + 16;
  float* rw    = (float*)(ws + o_rw);
  int* sel     = (int*)(ws + o_sel);
  float* sgate = (float*)(ws + o_sg);
  int* tok     = (int*)(ws + o_tok);
  int* s2t     = (int*)(ws + o_s2t);

  dim3 tb(32, 8, 1);

  hipMemsetAsync(counts, 0, 64, stream);  // counts + cursor

  // weight conversion + transpose (fp32 [R][C] -> bf16 [C][R])
  transpose_cvt_kernel<<<dim3(2 * ISH / 32, H_DIM / 32, 1), tb, 0, stream>>>(
      Wsgu, WsguT, H_DIM, 2 * ISH, 0, 0);
  transpose_cvt_kernel<<<dim3(H_DIM / 32, ISH / 32, 1), tb, 0, stream>>>(
      Wsd, WsdT, ISH, H_DIM, 0, 0);
  transpose_cvt_kernel<<<dim3(2 * IMOE / 32, H_DIM / 32, NEXP), tb, 0, stream>>>(
      Wegu, WeguT, H_DIM, 2 * IMOE, (long)H_DIM * 2 * IMOE, (long)2 * IMOE * H_DIM);
  transpose_cvt_kernel<<<dim3(H_DIM / 32, IMOE / 32, NEXP), tb, 0, stream>>>(
      Wed, WedT, IMOE, H_DIM, (long)IMOE * H_DIM, (long)H_DIM * IMOE);

  cvt_x_kernel<<<(T_TOK * H_DIM / 4) / 256, 256, 0, stream>>>(x, xbf, T_TOK * H_DIM / 4);

  router_kernel<<<T_TOK, 256, 0, stream>>>(x, Wr, Wsg, rw, sel, sgate, counts);
  scan_kernel<<<1, 64, 0, stream>>>(counts, offsets);
  scatter_kernel<<<(T_TOK + 255) / 256, 256, 0, stream>>>(sel, offsets, cursor, tok, s2t);

  // shared expert: gu = x @ Wsgu  [T, 2*ISH] (bf16)
  gemm_bt_kernel<0, false, false><<<dim3(T_TOK / 128, 2 * ISH / 128, 1), 256, 0, stream>>>(
      xbf, WsguT, gu_sh, T_TOK, 2 * ISH, H_DIM, nullptr, nullptr, nullptr, nullptr, 0);
  silu_mul_kernel<<<(T_TOK * (ISH / 4)) / 256, 256, 0, stream>>>(gu_sh, h_sh, T_TOK, ISH);
  // shared down + sigmoid-gate epilogue -> d_out (fp32)
  gemm_bt_kernel<1, false, false><<<dim3(T_TOK / 128, H_DIM / 128, 1), 256, 0, stream>>>(
      h_sh, WsdT, out, T_TOK, H_DIM, ISH, nullptr, nullptr, nullptr, sgate, 0);

  // routed experts: gathered gate_up -> gu_e (bf16)
  gemm_bt_kernel<0, true, true><<<dim3(T_TOK / 128, 2 * IMOE / 128, NEXP), 256, 0, stream>>>(
      xbf, WeguT, gu_e, T_TOK, 2 * IMOE, H_DIM, counts, offsets, tok, nullptr,
      (long)2 * IMOE * H_DIM);
  silu_mul_kernel<<<(TK_TOT * (IMOE / 4)) / 256, 256, 0, stream>>>(gu_e, h_e, TK_TOT, IMOE);
  // expert down -> eo (fp32)
  gemm_bt_kernel<2, true, false><<<dim3(T_TOK / 128, H_DIM / 128, NEXP), 256, 0, stream>>>(
      h_e, WedT, eo, T_TOK, H_DIM, IMOE, counts, offsets, nullptr, nullptr,
      (long)H_DIM * IMOE);

  combine_kernel<<<(T_TOK * H_DIM / 4) / 256, 256, 0, stream>>>(out, eo, s2t, rw);
}

// Round 2
// 760.303 us; speedup vs baseline: 1.1233x; 1.1233x over previous
//
#include <hip/hip_runtime.h>
#include <cstdio>

// Qwen2 MoE sparse block, MI355X gfx950.
// Round 2: GEMMs moved to 256x256-tile, BK=32, 4-LDS-buffer deep pipeline
// (T3+T4+T5 per guide): counted vmcnt(8), raw s_barrier, setprio around MFMA,
// XOR k-chunk swizzle (inverse applied on global source, rule 21).
// Shared-down uses split-K=4 with gated atomic adds into zeroed d_out.

#define H_DIM 2048
#define IMOE  1408
#define ISH   5632
#define NEXP  8
#define T_TOK 2048
#define TK_TOT (T_TOK * 2)

typedef __attribute__((ext_vector_type(8))) short short8;
typedef __attribute__((ext_vector_type(8))) __bf16 bf16x8;
typedef __attribute__((ext_vector_type(4))) float f32x4;

__device__ __forceinline__ float bf2f(unsigned short u) {
  union { unsigned int i; float f; } v; v.i = ((unsigned int)u) << 16; return v.f;
}
__device__ __forceinline__ unsigned short f2bf(float f) {
  union { float f; unsigned int i; } v; v.f = f;
  unsigned int x = v.i;
  return (unsigned short)((x + 0x7fffu + ((x >> 16) & 1u)) >> 16);
}

__device__ __forceinline__ f32x4 MFMA16(short8 a, short8 b, f32x4 c) {
  return __builtin_amdgcn_mfma_f32_16x16x32_bf16(
      __builtin_bit_cast(bf16x8, a), __builtin_bit_cast(bf16x8, b), c, 0, 0, 0);
}

__device__ __forceinline__ void gload_lds16(const unsigned short* g, unsigned short* l) {
  __builtin_amdgcn_global_load_lds(
      (const __attribute__((address_space(1))) unsigned int*)g,
      (__attribute__((address_space(3))) unsigned int*)l, 16, 0, 0);
}

__device__ __forceinline__ float silu_f(float x) { return x / (1.0f + __expf(-x)); }

#define SBAR()   asm volatile("s_barrier" ::: "memory")
#define VMCNT(n) asm volatile("s_waitcnt vmcnt(" #n ")" ::: "memory")

// ---------------- conversion kernels ----------------

__global__ __launch_bounds__(256)
void transpose_cvt_kernel(const float* __restrict__ src, unsigned short* __restrict__ dst,
                          int R, int C, long sStride, long dStride) {
  src += (long)blockIdx.z * sStride;
  dst += (long)blockIdx.z * dStride;
  __shared__ float tile[32][33];
  int tx = threadIdx.x, ty = threadIdx.y;           // 32 x 8
  int x = blockIdx.x * 32 + tx;
  int yb = blockIdx.y * 32;
#pragma unroll
  for (int j = 0; j < 4; j++) {
    int y = yb + ty + j * 8;
    tile[ty + j * 8][tx] = src[(long)y * C + x];
  }
  __syncthreads();
  int c = blockIdx.x * 32 + ty;
  int r = yb + tx;
#pragma unroll
  for (int j = 0; j < 4; j++) {
    dst[(long)(c + j * 8) * R + r] = f2bf(tile[tx][ty + j * 8]);
  }
}

__global__ __launch_bounds__(256)
void cvt_x_kernel(const float* __restrict__ x, unsigned short* __restrict__ xb, int total4) {
  int i = blockIdx.x * 256 + threadIdx.x;
  if (i >= total4) return;
  float4 v = ((const float4*)x)[i];
  ushort4 o;
  o.x = f2bf(v.x); o.y = f2bf(v.y); o.z = f2bf(v.z); o.w = f2bf(v.w);
  ((ushort4*)xb)[i] = o;
}

// ---------------- routing ----------------

__global__ __launch_bounds__(256)
void router_kernel(const float* __restrict__ x, const float* __restrict__ Wr,
                   const float* __restrict__ Wsg, float* __restrict__ rw,
                   int* __restrict__ sel, float* __restrict__ sgate_sig,
                   int* __restrict__ counts) {
  int t = blockIdx.x;
  const float* xr = x + (long)t * H_DIM;
  float p[9];
#pragma unroll
  for (int e = 0; e < 9; e++) p[e] = 0.0f;
  for (int h = threadIdx.x; h < H_DIM; h += 256) {
    float xv = xr[h];
#pragma unroll
    for (int e = 0; e < 8; e++) p[e] += xv * Wr[e * H_DIM + h];
    p[8] += xv * Wsg[h];
  }
#pragma unroll
  for (int e = 0; e < 9; e++)
    for (int off = 32; off > 0; off >>= 1)
      p[e] += __shfl_down(p[e], off, 64);
  __shared__ float red[4][9];
  int wave = threadIdx.x >> 6, lane = threadIdx.x & 63;
  if (lane == 0) {
#pragma unroll
    for (int e = 0; e < 9; e++) red[wave][e] = p[e];
  }
  __syncthreads();
  if (threadIdx.x == 0) {
    float lg[9];
#pragma unroll
    for (int e = 0; e < 9; e++) lg[e] = red[0][e] + red[1][e] + red[2][e] + red[3][e];
    float m = lg[0];
#pragma unroll
    for (int e = 1; e < 8; e++) m = fmaxf(m, lg[e]);
    float pr[8], s = 0.0f;
#pragma unroll
    for (int e = 0; e < 8; e++) { pr[e] = expf(lg[e] - m); s += pr[e]; }
    float inv = 1.0f / s;
#pragma unroll
    for (int e = 0; e < 8; e++) pr[e] *= inv;
    int i0 = 0;
#pragma unroll
    for (int e = 1; e < 8; e++) if (pr[e] > pr[i0]) i0 = e;
    int i1 = (i0 == 0) ? 1 : 0;
#pragma unroll
    for (int e = 0; e < 8; e++) if (e != i0 && pr[e] > pr[i1]) i1 = e;
    rw[t * 2] = pr[i0]; rw[t * 2 + 1] = pr[i1];
    sel[t * 2] = i0;    sel[t * 2 + 1] = i1;
    sgate_sig[t] = 1.0f / (1.0f + expf(-lg[8]));
    atomicAdd(&counts[i0], 1);
    atomicAdd(&counts[i1], 1);
  }
}

__global__ void scan_kernel(const int* __restrict__ counts, int* __restrict__ offsets) {
  if (threadIdx.x == 0 && blockIdx.x == 0) {
    int s = 0;
    for (int e = 0; e < NEXP; e++) { offsets[e] = s; s += counts[e]; }
    offsets[NEXP] = s;
  }
}

__global__ __launch_bounds__(256)
void scatter_kernel(const int* __restrict__ sel, const int* __restrict__ offsets,
                    int* __restrict__ cursor, int* __restrict__ tok_of_slot,
                    int* __restrict__ slot_of_tok) {
  int t = blockIdx.x * 256 + threadIdx.x;
  if (t >= T_TOK) return;
#pragma unroll
  for (int k = 0; k < 2; k++) {
    int e = sel[t * 2 + k];
    int pos = atomicAdd(&cursor[e], 1);
    int slot = offsets[e] + pos;
    tok_of_slot[slot] = t;
    slot_of_tok[t * 2 + k] = slot;
  }
}

// ---------------- 256x256 deep-pipelined GEMM ----------------
// C[M,N] = A[M,K](bf16) * BT[N,K]^T(bf16)
// 512 thr = 8 waves (2M x 4N), wave output 128x64. BK=32, 4 LDS buffers
// (4 x (A 16KB + B 16KB) = 128KB). Pipeline depth 3: while computing tile t,
// stage tile t+3 into buf[(t+3)&3] (reuse distance 4 => WAR-safe).
// vmcnt(8) once per tile keeps tiles t+2,t+3 (4 loads each) in flight.
// EPI: 0 = store bf16, 1 = unsafeAtomicAdd fp32 * rowscale[row], 2 = store fp32
template <int EPI, bool EXPERT, bool GATHER>
__global__ __launch_bounds__(512, 2)
void gemm8_kernel(const unsigned short* __restrict__ A,
                  const unsigned short* __restrict__ BT,
                  void* __restrict__ Cv,
                  int N, int Kld, int KLEN, int M,
                  const int* __restrict__ counts, const int* __restrict__ offsets,
                  const int* __restrict__ tok_of_slot,
                  const float* __restrict__ rowscale, long bt_estride) {
  __shared__ unsigned short lds8[65536];  // 128 KiB: buf b at b*16384 (A), +8192 (B)

  int cnt = M, rowbase = 0, k0 = 0;
  const unsigned short* bt = BT;
  if constexpr (EXPERT) {
    int e = blockIdx.z;
    cnt = counts[e];
    rowbase = offsets[e];
    bt += (long)e * bt_estride;
  } else {
    k0 = blockIdx.z * KLEN;   // split-K chunk (z==0 -> 0)
  }
  int row0 = blockIdx.x * 256;
  if (row0 >= cnt) return;
  int col0 = blockIdx.y * 256;

  int tid = threadIdx.x, wave = tid >> 6, lane = tid & 63;
  int NT = KLEN / 32;

  // ---- staging setup: 2 A-insts + 2 B-insts per tile, 8KB (128 rows) each ----
  // inst i: local row r = i*128 + tid/4; linear k-chunk tid&3 holds global
  // k-chunk (tid&3)^((r>>1)&3)  (inverse swizzle on source, rule 21).
  const unsigned short* aSrc[2];
  const unsigned short* bSrc[2];
#pragma unroll
  for (int i = 0; i < 2; i++) {
    int r = i * 128 + (tid >> 2);
    int sw = (((tid & 3) ^ ((r >> 1) & 3)) * 8);
    long arow;
    if constexpr (EXPERT) {
      int s = rowbase + min(row0 + r, cnt - 1);
      arow = GATHER ? tok_of_slot[s] : s;
    } else {
      arow = row0 + r;
    }
    aSrc[i] = A + arow * (long)Kld + k0 + sw;
    bSrc[i] = bt + (long)(col0 + r) * Kld + k0 + sw;
  }
  // LDS dest bases (wave-uniform), in shorts, within a 16384-short buffer
  int dA0 = wave * 512, dA1 = 4096 + wave * 512;
  int dB0 = 8192 + wave * 512, dB1 = 12288 + wave * 512;

  auto STAGE_A = [&](int u) {
    int b2 = (u & 3) * 16384;
    long kk = (long)min(u, NT - 1) * 32;
    gload_lds16(aSrc[0] + kk, &lds8[b2 + dA0]);
    gload_lds16(aSrc[1] + kk, &lds8[b2 + dA1]);
  };
  auto STAGE_B = [&](int u) {
    int b2 = (u & 3) * 16384;
    long kk = (long)min(u, NT - 1) * 32;
    gload_lds16(bSrc[0] + kk, &lds8[b2 + dB0]);
    gload_lds16(bSrc[1] + kk, &lds8[b2 + dB1]);
  };

  // ---- fragment read offsets (swizzled), in shorts ----
  int wr = wave >> 2, wc = wave & 3;
  int fr = lane & 15, fg = lane >> 4;
  int addrA0[4], addrA1[4], addrB[4];
#pragma unroll
  for (int m = 0; m < 4; m++) {
    int rl0 = wr * 128 + m * 16 + fr;
    int rl1 = rl0 + 64;
    int cl  = wc * 64 + m * 16 + fr;
    addrA0[m] = rl0 * 32 + ((fg ^ ((rl0 >> 1) & 3)) * 8);
    addrA1[m] = rl1 * 32 + ((fg ^ ((rl1 >> 1) & 3)) * 8);
    addrB[m]  = 8192 + cl * 32 + ((fg ^ ((cl >> 1) & 3)) * 8);
  }

  // ---- prologue: stage tiles 0,1,2 (12 loads); wait tile 0 (leave 8) ----
  STAGE_A(0); STAGE_B(0);
  STAGE_A(1); STAGE_B(1);
  STAGE_A(2); STAGE_B(2);
  VMCNT(8);
  SBAR();

  f32x4 acc[8][4] = {};

  for (int t = 0; t < NT; t++) {
    int b = (t & 3) * 16384;
    int u = t + 3;
    // ---- phase A: B-frags + A-half0, stage A of t+3, 16 MFMA ----
    short8 Bf[4], Af[4];
#pragma unroll
    for (int n = 0; n < 4; n++) Bf[n] = *(const short8*)&lds8[b + addrB[n]];
#pragma unroll
    for (int m = 0; m < 4; m++) Af[m] = *(const short8*)&lds8[b + addrA0[m]];
    STAGE_A(u);
    SBAR();
    __builtin_amdgcn_s_setprio(1);
#pragma unroll
    for (int m = 0; m < 4; m++)
#pragma unroll
      for (int n = 0; n < 4; n++)
        acc[m][n] = MFMA16(Af[m], Bf[n], acc[m][n]);
    __builtin_amdgcn_s_setprio(0);
    SBAR();
    // ---- phase B: A-half1, stage B of t+3, 16 MFMA, counted vmcnt ----
#pragma unroll
    for (int m = 0; m < 4; m++) Af[m] = *(const short8*)&lds8[b + addrA1[m]];
    STAGE_B(u);
    SBAR();
    __builtin_amdgcn_s_setprio(1);
#pragma unroll
    for (int m = 0; m < 4; m++)
#pragma unroll
      for (int n = 0; n < 4; n++)
        acc[4 + m][n] = MFMA16(Af[m], Bf[n], acc[4 + m][n]);
    __builtin_amdgcn_s_setprio(0);
    VMCNT(8);   // tile t+1 (issued 2 tiles ago) now resident; t+2,t+3 in flight
    SBAR();
  }
  VMCNT(0);   // drain dummy tail stages before exit

  // ---- epilogue ----
  int rowguard = cnt - row0;
#pragma unroll
  for (int mq = 0; mq < 8; mq++) {
    int rl = wr * 128 + (mq >> 2) * 64 + (mq & 3) * 16 + fg * 4;
#pragma unroll
    for (int n = 0; n < 4; n++) {
      int cg = col0 + wc * 64 + n * 16 + fr;
      f32x4 v = acc[mq][n];
#pragma unroll
      for (int j = 0; j < 4; j++) {
        int r = rl + j;
        if (r < rowguard) {
          long orow = (long)rowbase + row0 + r;
          long ci = orow * (long)N + cg;
          if constexpr (EPI == 0)      ((unsigned short*)Cv)[ci] = f2bf(v[j]);
          else if constexpr (EPI == 2) ((float*)Cv)[ci] = v[j];
          else unsafeAtomicAdd(&((float*)Cv)[ci], v[j] * rowscale[orow]);
        }
      }
    }
  }
}

// ---------------- elementwise ----------------

__global__ __launch_bounds__(256)
void silu_mul_kernel(const unsigned short* __restrict__ gu, unsigned short* __restrict__ h,
                     int rows, int I) {
  int i = blockIdx.x * 256 + threadIdx.x;
  int i4 = I >> 2;
  if (i >= rows * i4) return;
  int row = i / i4;
  int ci = (i - row * i4) * 4;
  const unsigned short* g = gu + (long)row * 2 * I + ci;
  ushort4 gv = *(const ushort4*)g;
  ushort4 uv = *(const ushort4*)(g + I);
  ushort4 o;
  o.x = f2bf(silu_f(bf2f(gv.x)) * bf2f(uv.x));
  o.y = f2bf(silu_f(bf2f(gv.y)) * bf2f(uv.y));
  o.z = f2bf(silu_f(bf2f(gv.z)) * bf2f(uv.z));
  o.w = f2bf(silu_f(bf2f(gv.w)) * bf2f(uv.w));
  *(ushort4*)(h + (long)row * I + ci) = o;
}

// out += w0*eo[s0] + w1*eo[s1]   (out already holds gated shared-expert sum)
__global__ __launch_bounds__(256)
void combine_kernel(float* __restrict__ out, const float* __restrict__ eo,
                    const int* __restrict__ slot_of_tok, const float* __restrict__ rw) {
  int i = blockIdx.x * 256 + threadIdx.x;
  const int h4n = H_DIM / 4;
  if (i >= T_TOK * h4n) return;
  int t = i / h4n;
  int h4 = i - t * h4n;
  int s0 = slot_of_tok[t * 2], s1 = slot_of_tok[t * 2 + 1];
  float w0 = rw[t * 2], w1 = rw[t * 2 + 1];
  float4 o = ((float4*)out)[i];
  float4 a = ((const float4*)eo)[(long)s0 * h4n + h4];
  float4 b = ((const float4*)eo)[(long)s1 * h4n + h4];
  o.x += w0 * a.x + w1 * b.x;
  o.y += w0 * a.y + w1 * b.y;
  o.z += w0 * a.z + w1 * b.z;
  o.w += w0 * a.w + w1 * b.w;
  ((float4*)out)[i] = o;
}

// ---------------- host ----------------

extern "C" void kernel_launch(void* const* d_in, const int* in_sizes, int n_in,
                              void* d_out, int out_size, void* d_ws, size_t ws_size,
                              hipStream_t stream) {
  (void)in_sizes; (void)n_in; (void)out_size;
  const float* x    = (const float*)d_in[0];
  const float* Wr   = (const float*)d_in[1];
  const float* Wsg  = (const float*)d_in[2];
  const float* Wsgu = (const float*)d_in[3];
  const float* Wsd  = (const float*)d_in[4];
  const float* Wegu = (const float*)d_in[5];
  const float* Wed  = (const float*)d_in[6];
  float* out = (float*)d_out;

  char* ws = (char*)d_ws;
  size_t off = 0;
  auto alloc = [&](size_t b) { size_t o = off; off += (b + 255) & ~(size_t)255; return o; };

  size_t o_xbf   = alloc((size_t)T_TOK * H_DIM * 2);
  size_t o_WsguT = alloc((size_t)2 * ISH * H_DIM * 2);       // aliased as eo later
  size_t o_WsdT  = alloc((size_t)H_DIM * ISH * 2);
  size_t o_WeguT = alloc((size_t)NEXP * 2 * IMOE * H_DIM * 2);
  size_t o_WedT  = alloc((size_t)NEXP * H_DIM * IMOE * 2);
  size_t o_gush  = alloc((size_t)T_TOK * 2 * ISH * 2);       // aliased as gu_e + h_e later
  size_t o_hsh   = alloc((size_t)T_TOK * ISH * 2);
  size_t o_ints  = alloc(256);
  size_t o_rw    = alloc((size_t)TK_TOT * 4);
  size_t o_sel   = alloc((size_t)TK_TOT * 4);
  size_t o_sg    = alloc((size_t)T_TOK * 4);
  size_t o_tok   = alloc((size_t)TK_TOT * 4);
  size_t o_s2t   = alloc((size_t)TK_TOT * 4);

  if (off > ws_size) {
    fprintf(stderr, "[moe kernel] workspace too small: need %zu have %zu\n", off, ws_size);
    return;
  }

  unsigned short* xbf   = (unsigned short*)(ws + o_xbf);
  unsigned short* WsguT = (unsigned short*)(ws + o_WsguT);
  unsigned short* WsdT  = (unsigned short*)(ws + o_WsdT);
  unsigned short* WeguT = (unsigned short*)(ws + o_WeguT);
  unsigned short* WedT  = (unsigned short*)(ws + o_WedT);
  unsigned short* gu_sh = (unsigned short*)(ws + o_gush);
  unsigned short* h_sh  = (unsigned short*)(ws + o_hsh);
  unsigned short* gu_e = (unsigned short*)(ws + o_gush);
  unsigned short* h_e  = (unsigned short*)(ws + o_gush + (size_t)TK_TOT * 2 * IMOE * 2);
  float* eo = (float*)(ws + o_WsguT);

  int* counts  = (int*)(ws + o_ints);
  int* cursor  = counts + 8;
  int* offsets = counts + 16;
  float* rw    = (float*)(ws + o_rw);
  int* sel     = (int*)(ws + o_sel);
  float* sgate = (float*)(ws + o_sg);
  int* tok     = (int*)(ws + o_tok);
  int* s2t     = (int*)(ws + o_s2t);

  dim3 tb(32, 8, 1);

  hipMemsetAsync(counts, 0, 64, stream);

  transpose_cvt_kernel<<<dim3(2 * ISH / 32, H_DIM / 32, 1), tb, 0, stream>>>(
      Wsgu, WsguT, H_DIM, 2 * ISH, 0, 0);
  transpose_cvt_kernel<<<dim3(H_DIM / 32, ISH / 32, 1), tb, 0, stream>>>(
      Wsd, WsdT, ISH, H_DIM, 0, 0);
  transpose_cvt_kernel<<<dim3(2 * IMOE / 32, H_DIM / 32, NEXP), tb, 0, stream>>>(
      Wegu, WeguT, H_DIM, 2 * IMOE, (long)H_DIM * 2 * IMOE, (long)2 * IMOE * H_DIM);
  transpose_cvt_kernel<<<dim3(H_DIM / 32, IMOE / 32, NEXP), tb, 0, stream>>>(
      Wed, WedT, IMOE, H_DIM, (long)IMOE * H_DIM, (long)H_DIM * IMOE);

  cvt_x_kernel<<<(T_TOK * H_DIM / 4) / 256, 256, 0, stream>>>(x, xbf, T_TOK * H_DIM / 4);

  router_kernel<<<T_TOK, 256, 0, stream>>>(x, Wr, Wsg, rw, sel, sgate, counts);
  scan_kernel<<<1, 64, 0, stream>>>(counts, offsets);
  scatter_kernel<<<(T_TOK + 255) / 256, 256, 0, stream>>>(sel, offsets, cursor, tok, s2t);

  // shared expert: gu = x @ Wsgu  [T, 2*ISH] bf16
  gemm8_kernel<0, false, false><<<dim3(T_TOK / 256, 2 * ISH / 256, 1), 512, 0, stream>>>(
      xbf, WsguT, gu_sh, 2 * ISH, H_DIM, H_DIM, T_TOK,
      nullptr, nullptr, nullptr, nullptr, 0);
  silu_mul_kernel<<<(T_TOK * (ISH / 4)) / 256, 256, 0, stream>>>(gu_sh, h_sh, T_TOK, ISH);

  // shared down, split-K=4, gated atomic accumulate into zeroed out
  hipMemsetAsync(out, 0, (size_t)T_TOK * H_DIM * 4, stream);
  gemm8_kernel<1, false, false><<<dim3(T_TOK / 256, H_DIM / 256, 4), 512, 0, stream>>>(
      h_sh, WsdT, out, H_DIM, ISH, ISH / 4, T_TOK,
      nullptr, nullptr, nullptr, sgate, 0);

  // routed experts
  gemm8_kernel<0, true, true><<<dim3(T_TOK / 256, 2 * IMOE / 256, NEXP), 512, 0, stream>>>(
      xbf, WeguT, gu_e, 2 * IMOE, H_DIM, H_DIM, 0,
      counts, offsets, tok, nullptr, (long)2 * IMOE * H_DIM);
  silu_mul_kernel<<<(TK_TOT * (IMOE / 4)) / 256, 256, 0, stream>>>(gu_e, h_e, TK_TOT, IMOE);
  gemm8_kernel<2, true, false><<<dim3(T_TOK / 256, H_DIM / 256, NEXP), 512, 0, stream>>>(
      h_e, WedT, eo, H_DIM, IMOE, IMOE, 0,
      counts, offsets, nullptr, nullptr, (long)H_DIM * IMOE);

  combine_kernel<<<(T_TOK * H_DIM / 4) / 256, 256, 0, stream>>>(out, eo, s2t, rw);
}